// Round 11
// baseline (166.257 us; speedup 1.0000x reference)
//
#include <hip/hip_runtime.h>
#include <hip/hip_bf16.h>

#define NUM_B 8
#define SEQ 1024
#define DIM 768
#define NH 12
#define DH 64

typedef __attribute__((ext_vector_type(8))) short bf16x8;
typedef __attribute__((ext_vector_type(4))) float floatx4;
typedef __attribute__((ext_vector_type(16))) float floatx16;
typedef __attribute__((ext_vector_type(4))) unsigned short ushortx4;
typedef __attribute__((ext_vector_type(8))) unsigned short ushortx8;

__device__ __forceinline__ unsigned short f2bf(float f) {
  unsigned u = __float_as_uint(f);
  u += 0x7FFFu + ((u >> 16) & 1u);   // round-to-nearest-even
  return (unsigned short)(u >> 16);
}

// async global->LDS, 16B per lane; LDS dest = wave-uniform base + lane*16
#define GLOAD16(g, l) __builtin_amdgcn_global_load_lds( \
    (const __attribute__((address_space(1))) unsigned int*)(g), \
    (__attribute__((address_space(3))) unsigned int*)(l), 16, 0, 0)

// ---------------- one-shot fp32 -> bf16 conversion (x, Wk, Wo) -------------
__global__ __launch_bounds__(256) void convert_kernel(
    const float* __restrict__ x, const float* __restrict__ Wk,
    const float* __restrict__ Wo, unsigned short* __restrict__ xb,
    unsigned short* __restrict__ Wkb, unsigned short* __restrict__ Wob)
{
  const int NX4 = (8192 * 768) / 4;
  const int NW4 = (768 * 768) / 4;
  int i = blockIdx.x * 256 + threadIdx.x;
  const float* s; unsigned short* d; int off;
  if (i < NX4)            { s = x;  d = xb;  off = i; }
  else if (i < NX4 + NW4) { s = Wk; d = Wkb; off = i - NX4; }
  else                    { s = Wo; d = Wob; off = i - NX4 - NW4; }
  float4 v = ((const float4*)s)[off];
  ushortx4 h;
  h.x = f2bf(v.x); h.y = f2bf(v.y); h.z = f2bf(v.z); h.w = f2bf(v.w);
  ((ushortx4*)d)[off] = h;
}

// ---------------- K projection + fused transpose ---------------------------
// 64(M) x 128(N), BK=64, dbuf swizzled global_load_lds, grid 768 (3/CU).
__global__ __launch_bounds__(256) void proj_k_kernel(
    const unsigned short* __restrict__ xb, const unsigned short* __restrict__ Wkb,
    const float* __restrict__ bk, unsigned short* __restrict__ Kbh,
    unsigned short* __restrict__ KbhT)
{
  __shared__ __align__(16) unsigned short smem[24576];   // 48 KB (2 x 24 KB)
  const int tid = threadIdx.x;
  const int lane = tid & 63;
  const int w = tid >> 6;
  const int wr = w >> 1, wc = w & 1;
  const int quad = lane >> 4, r16 = lane & 15;
  const int rs = r16 & 7;
  const int m0 = blockIdx.x * 64, n0 = blockIdx.y * 128;
  const int wbase = (tid & ~63);

  floatx4 acc[2][4] = {};

  auto stage = [&](int kt, int buf) {
    unsigned short* As = smem + buf * 12288;
    unsigned short* Bs = As + 4096;
#pragma unroll
    for (int i = 0; i < 2; ++i) {
      int c = tid + i * 256;
      int row = c >> 3, g = (c & 7) ^ (row & 7);
      GLOAD16(xb + (size_t)(m0 + row) * DIM + kt + g * 8,
              As + (size_t)(wbase + i * 256) * 8);
    }
#pragma unroll
    for (int i = 0; i < 4; ++i) {
      int c = tid + i * 256;
      int row = c >> 3, g = (c & 7) ^ (row & 7);
      GLOAD16(Wkb + (size_t)(n0 + row) * DIM + kt + g * 8,
              Bs + (size_t)(wbase + i * 256) * 8);
    }
  };

  stage(0, 0);
  int buf = 0;
  for (int it = 0; it < 12; ++it) {
    __syncthreads();
    if (it + 1 < 12) stage((it + 1) * 64, buf ^ 1);
    const unsigned short* As = smem + buf * 12288;
    const unsigned short* Bs = As + 4096;
    bf16x8 af[2][2], bfm[4][2];
#pragma unroll
    for (int mi = 0; mi < 2; ++mi)
#pragma unroll
      for (int kc = 0; kc < 2; ++kc)
        af[mi][kc] = *(const bf16x8*)&As[(wr * 32 + mi * 16 + r16) * 64 + ((kc * 4 + quad) ^ rs) * 8];
#pragma unroll
    for (int ni = 0; ni < 4; ++ni)
#pragma unroll
      for (int kc = 0; kc < 2; ++kc)
        bfm[ni][kc] = *(const bf16x8*)&Bs[(wc * 64 + ni * 16 + r16) * 64 + ((kc * 4 + quad) ^ rs) * 8];
#pragma unroll
    for (int mi = 0; mi < 2; ++mi)
#pragma unroll
      for (int ni = 0; ni < 4; ++ni) {
        acc[mi][ni] = __builtin_amdgcn_mfma_f32_16x16x32_bf16(af[mi][0], bfm[ni][0], acc[mi][ni], 0, 0, 0);
        acc[mi][ni] = __builtin_amdgcn_mfma_f32_16x16x32_bf16(af[mi][1], bfm[ni][1], acc[mi][ni], 0, 0, 0);
      }
    buf ^= 1;
  }

  __syncthreads();                       // reuse smem as Ct [128 n][72]
  unsigned short* Ct = smem;
  const int bb = m0 >> 10, l0 = m0 & 1023;
#pragma unroll
  for (int mi = 0; mi < 2; ++mi)
#pragma unroll
    for (int ni = 0; ni < 4; ++ni) {
      int col = n0 + wc * 64 + ni * 16 + r16;   // j = h*64+dh
      float bias = bk[col];
      int hh = col >> 6, dd = col & 63;
      ushortx4 pk;
#pragma unroll
      for (int r = 0; r < 4; ++r) {
        int mrow = wr * 32 + mi * 16 + quad * 4 + r;
        unsigned short us = f2bf(acc[mi][ni][r] + bias);
        Kbh[((size_t)(bb * NH + hh) * SEQ + l0 + mrow) * DH + dd] = us;
        pk[r] = us;
      }
      *(ushortx4*)&Ct[(wc * 64 + ni * 16 + r16) * 72 + wr * 32 + mi * 16 + quad * 4] = pk;
    }
  __syncthreads();
#pragma unroll
  for (int i = 0; i < 4; ++i) {
    int c = tid + i * 256;
    int row = c >> 3, ch = c & 7;
    ushortx8 v = *(const ushortx8*)&Ct[row * 72 + ch * 8];
    int j = n0 + row;
    int hh = j >> 6, dd = j & 63;
    *(ushortx8*)&KbhT[((size_t)(bb * NH + hh) * DH + dd) * SEQ + l0 + ch * 8] = v;
  }
}

// ---------------- fused attention ------------------------------------------
// 1-D grid 768 (3 blocks/CU, balanced), 256 threads = 4 waves x 32 q.
// 32x32x16 MFMAs with SWAPPED QK^T; softmax fully in-register.
// P cross-half exchange via v_permlane32_swap_b32 (VALU), CORRECTED
// operand order: HW semantics are vdst.HI <-> vsrc.LO (R10's lo<->hi
// assumption failed refcheck; the R9-verified word requirements force
// this direction). After swap(w0, w2):
//   w0 = {lo: own pk0,     hi: partner pk2} = B word0  (R9-verified value)
//   w2 = {lo: partner pk0, hi: own pk2    } = B word2  (R9-verified value)
// XCD decode: 8 q-tiles of each bh on one XCD (Lb%8==bh%8), K/KT L2-resident.
__global__ __launch_bounds__(256) void attn_kernel(
    const unsigned short* __restrict__ Kbh, const unsigned short* __restrict__ KbhT,
    const int* __restrict__ mask, unsigned short* __restrict__ wV)
{
  __shared__ __align__(16) unsigned short smem[16384];   // 32 KB: Ks/KTs dbuf

  const int tid = threadIdx.x;
  const int lane = tid & 63;
  const int w = tid >> 6;                // 0..3
  const int q = lane & 31;               // lane's q within the wave's 32-q tile
  const int hh = lane >> 5;              // half-wave (k-slot group)
  const int q7 = q & 7;                  // XOR swizzle key (row&7)
  // XCD-aware bijective decode (XCD = linear%8 round-robin assumption):
  const int Lb = blockIdx.x;
  const int qt = (Lb >> 3) & 7;
  const int bh = (Lb >> 6) * 8 + (Lb & 7);
  const int b = bh / NH, h = bh % NH;
  const unsigned short* Kb  = Kbh  + (size_t)bh * SEQ * DH;
  const unsigned short* KbT = KbhT + (size_t)bh * DH * SEQ;
  const int q0 = qt * 128;
  const int qw = w * 32;                 // wave's 32-q range within tile
  const int wbase = (tid & ~63);
  // 1/sqrt(768) * log2(e): exp(x*s) == exp2(x*s*log2e)
  const float SCALE2 = 0.036084391824351615f * 1.4426950408889634f;

  // mask folded into scale: masked row -> Q=0 -> St=0 -> p=1 (uniform softmax)
  const float scm = (mask[b * SEQ + q0 + qw + q] != 0) ? SCALE2 : 0.0f;

  // Q fragments, pre-scaled by scm (B-operand: col=q=lane&31, k=d=s*16+hh*8+j)
  bf16x8 aq[4];
#pragma unroll
  for (int s = 0; s < 4; ++s) {
    bf16x8 v = *(const bf16x8*)(Kb + (size_t)(q0 + qw + q) * DH + s * 16 + hh * 8);
    ushortx8 u; __builtin_memcpy(&u, &v, 16);
    ushortx8 o;
#pragma unroll
    for (int j = 0; j < 8; j += 2) {
      float f0 = __uint_as_float(((unsigned)u[j]) << 16) * scm;
      float f1 = __uint_as_float(((unsigned)u[j + 1]) << 16) * scm;
      __hip_bfloat162 hcv = __float22bfloat162_rn(make_float2(f0, f1));
      unsigned hu; __builtin_memcpy(&hu, &hcv, 4);
      o[j] = (unsigned short)(hu & 0xffffu);
      o[j + 1] = (unsigned short)(hu >> 16);
    }
    __builtin_memcpy(&aq[s], &o, 16);
  }

  floatx16 accO[2] = {};                 // O^T[d0*32+row][q], d0 = 0,1
  float psum = 0.0f;

  auto stage = [&](int kt, int buf) {
    unsigned short* Ks  = smem + buf * 4096;
    unsigned short* KTs = smem + 8192 + buf * 4096;
    // 256 threads x 16B x 2 passes per 64x64 bf16 tile
#pragma unroll
    for (int i = 0; i < 2; ++i) {
      int c = tid + i * 256;
      int row = c >> 3, g = (c & 7) ^ (row & 7);
      GLOAD16(Kb + (size_t)(kt + row) * DH + g * 8,
              Ks + (size_t)(wbase + i * 256) * 8);
    }
#pragma unroll
    for (int i = 0; i < 2; ++i) {
      int c = tid + i * 256;
      int row = c >> 3, g = (c & 7) ^ (row & 7);
      GLOAD16(KbT + (size_t)row * SEQ + kt + g * 8,
              KTs + (size_t)(wbase + i * 256) * 8);
    }
  };

  stage(0, 0);
  int buf = 0;
  for (int it = 0; it < SEQ / 64; ++it) {
    __syncthreads();
    if (it + 1 < SEQ / 64) stage((it + 1) * 64, buf ^ 1);
    const unsigned short* Ks  = smem + buf * 4096;
    const unsigned short* KTs = smem + 8192 + buf * 4096;

    bf16x8 pa[4];                        // PV B-frags: key steps s=0..3

#pragma unroll
    for (int kt = 0; kt < 2; ++kt) {
      // St[key][q] over 32 keys: A = K-frag (row=key=kt*32+q', k=d), B = aq
      floatx16 St = {};
      __builtin_amdgcn_s_setprio(1);
#pragma unroll
      for (int s = 0; s < 4; ++s) {
        bf16x8 kf = *(const bf16x8*)&Ks[(kt * 32 + q) * 64 + ((2 * s + hh) ^ q7) * 8];
        St = __builtin_amdgcn_mfma_f32_32x32x16_bf16(kf, aq[s], St, 0, 0, 0);
      }
      __builtin_amdgcn_s_setprio(0);

      // softmax partials in-register; pack pairs to bf16.
      // reg r -> key kt*32 + (r&3)+8*(r>>2)+4*hh
      unsigned pk[8];
#pragma unroll
      for (int j = 0; j < 8; ++j) {
        float pa_ = __builtin_amdgcn_exp2f(St[2 * j]);
        float pb_ = __builtin_amdgcn_exp2f(St[2 * j + 1]);
        psum += pa_ + pb_;
        __hip_bfloat162 hcv = __float22bfloat162_rn(make_float2(pa_, pb_));
        __builtin_memcpy(&pk[j], &hcv, 4);
      }
      // cross-half exchange via permlane32_swap: vdst.HI <-> vsrc.LO.
      // swap(w0, w2): w0.hi gets partner pk2, w2.lo gets partner pk0;
      // w0.lo / w2.hi keep own pk0 / pk2 -> exactly the R9-verified words.
      unsigned w0 = pk[0], w1 = pk[1], w2 = pk[2], w3 = pk[3];
      unsigned w4 = pk[4], w5 = pk[5], w6 = pk[6], w7 = pk[7];
      asm("v_permlane32_swap_b32 %0, %1" : "+v"(w0), "+v"(w2));
      asm("v_permlane32_swap_b32 %0, %1" : "+v"(w1), "+v"(w3));
      asm("v_permlane32_swap_b32 %0, %1" : "+v"(w4), "+v"(w6));
      asm("v_permlane32_swap_b32 %0, %1" : "+v"(w5), "+v"(w7));
      uint4 B0 = make_uint4(w0, w1, w2, w3);
      uint4 B1 = make_uint4(w4, w5, w6, w7);
      __builtin_memcpy(&pa[kt * 2 + 0], &B0, 16);
      __builtin_memcpy(&pa[kt * 2 + 1], &B1, 16);
    }

    // O^T[d][q] += V^T[d][key] P^T[key][q]; A = V^T-frag from KTs
    __builtin_amdgcn_s_setprio(1);
#pragma unroll
    for (int d0 = 0; d0 < 2; ++d0)
#pragma unroll
      for (int s = 0; s < 4; ++s) {
        bf16x8 vf = *(const bf16x8*)&KTs[(d0 * 32 + q) * 64 + ((2 * s + hh) ^ q7) * 8];
        accO[d0] = __builtin_amdgcn_mfma_f32_32x32x16_bf16(vf, pa[s], accO[d0], 0, 0, 0);
      }
    __builtin_amdgcn_s_setprio(0);
    buf ^= 1;
  }

  // lane holds sums over its 16-key half (all tiles); partner has the rest.
  psum += __shfl_xor(psum, 32);
  float rinv = 1.0f / psum;

  // accO C-layout: col=q (this lane's q), row d = (r&3)+8*(r>>2)+4*hh
  const size_t orow = (size_t)(b * SEQ + q0 + qw + q) * DIM + h * DH;
#pragma unroll
  for (int d0 = 0; d0 < 2; ++d0)
#pragma unroll
    for (int rg = 0; rg < 4; ++rg) {
      ushortx4 st;
#pragma unroll
      for (int i = 0; i < 4; ++i)
        st[i] = f2bf(accO[d0][rg * 4 + i] * rinv);
      *(ushortx4*)&wV[orow + d0 * 32 + rg * 8 + hh * 4] = st;
    }
}

// ---------------- output projection: out = wV @ Wo^T + bo (fp32) -----------
__global__ __launch_bounds__(256) void proj_o_kernel(
    const unsigned short* __restrict__ wVb, const unsigned short* __restrict__ Wob,
    const float* __restrict__ bo, float* __restrict__ out)
{
  __shared__ __align__(16) unsigned short smem[24576];   // 48 KB
  const int tid = threadIdx.x;
  const int lane = tid & 63;
  const int w = tid >> 6;
  const int wr = w >> 1, wc = w & 1;
  const int quad = lane >> 4, r16 = lane & 15;
  const int rs = r16 & 7;
  const int m0 = blockIdx.x * 64, n0 = blockIdx.y * 128;
  const int wbase = (tid & ~63);

  floatx4 acc[2][4] = {};

  auto stage = [&](int kt, int buf) {
    unsigned short* As = smem + buf * 12288;
    unsigned short* Bs = As + 4096;
#pragma unroll
    for (int i = 0; i < 2; ++i) {
      int c = tid + i * 256;
      int row = c >> 3, g = (c & 7) ^ (row & 7);
      GLOAD16(wVb + (size_t)(m0 + row) * DIM + kt + g * 8,
              As + (size_t)(wbase + i * 256) * 8);
    }
#pragma unroll
    for (int i = 0; i < 4; ++i) {
      int c = tid + i * 256;
      int row = c >> 3, g = (c & 7) ^ (row & 7);
      GLOAD16(Wob + (size_t)(n0 + row) * DIM + kt + g * 8,
              Bs + (size_t)(wbase + i * 256) * 8);
    }
  };

  stage(0, 0);
  int buf = 0;
  for (int it = 0; it < 12; ++it) {
    __syncthreads();
    if (it + 1 < 12) stage((it + 1) * 64, buf ^ 1);
    const unsigned short* As = smem + buf * 12288;
    const unsigned short* Bs = As + 4096;
    bf16x8 af[2][2], bfm[4][2];
#pragma unroll
    for (int mi = 0; mi < 2; ++mi)
#pragma unroll
      for (int kc = 0; kc < 2; ++kc)
        af[mi][kc] = *(const bf16x8*)&As[(wr * 32 + mi * 16 + r16) * 64 + ((kc * 4 + quad) ^ rs) * 8];
#pragma unroll
    for (int ni = 0; ni < 4; ++ni)
#pragma unroll
      for (int kc = 0; kc < 2; ++kc)
        bfm[ni][kc] = *(const bf16x8*)&Bs[(wc * 64 + ni * 16 + r16) * 64 + ((kc * 4 + quad) ^ rs) * 8];
#pragma unroll
    for (int mi = 0; mi < 2; ++mi)
#pragma unroll
      for (int ni = 0; ni < 4; ++ni) {
        acc[mi][ni] = __builtin_amdgcn_mfma_f32_16x16x32_bf16(af[mi][0], bfm[ni][0], acc[mi][ni], 0, 0, 0);
        acc[mi][ni] = __builtin_amdgcn_mfma_f32_16x16x32_bf16(af[mi][1], bfm[ni][1], acc[mi][ni], 0, 0, 0);
      }
    buf ^= 1;
  }

#pragma unroll
  for (int mi = 0; mi < 2; ++mi)
#pragma unroll
    for (int ni = 0; ni < 4; ++ni) {
      int col = n0 + wc * 64 + ni * 16 + r16;
      float bias = bo[col];
#pragma unroll
      for (int r = 0; r < 4; ++r) {
        int row = m0 + wr * 32 + mi * 16 + quad * 4 + r;
        out[(size_t)row * DIM + col] = acc[mi][ni][r] + bias;
      }
    }
}

extern "C" void kernel_launch(void* const* d_in, const int* in_sizes, int n_in,
                              void* d_out, int out_size, void* d_ws, size_t ws_size,
                              hipStream_t stream) {
  // inputs: x, attention_mask, Wq, bq, Wk, bk, Wv, bv, Wo, bo  (Q dead; V==K)
  const float* x  = (const float*)d_in[0];
  const int* mask = (const int*)d_in[1];
  const float* Wk = (const float*)d_in[4];
  const float* bk = (const float*)d_in[5];
  const float* Wo = (const float*)d_in[8];
  const float* bo = (const float*)d_in[9];
  float* out = (float*)d_out;

  unsigned short* p = (unsigned short*)d_ws;
  unsigned short* xb   = p;  p += (size_t)8192 * 768;
  unsigned short* Wkb  = p;  p += (size_t)768 * 768;
  unsigned short* Wob  = p;  p += (size_t)768 * 768;
  unsigned short* Kbh  = p;  p += (size_t)NUM_B * NH * SEQ * DH;
  unsigned short* KbhT = p;  p += (size_t)NUM_B * NH * SEQ * DH;
  unsigned short* wVb  = p;  // [8192][768]

  convert_kernel<<<7296, 256, 0, stream>>>(x, Wk, Wo, xb, Wkb, Wob);
  proj_k_kernel<<<dim3(128, 6), 256, 0, stream>>>(xb, Wkb, bk, Kbh, KbhT);
  attn_kernel<<<768, 256, 0, stream>>>(Kbh, KbhT, mask, wVb);
  proj_o_kernel<<<dim3(128, 6), 256, 0, stream>>>(wVb, Wob, bo, out);
}

// Round 12
// 164.267 us; speedup vs baseline: 1.0121x; 1.0121x over previous
//
#include <hip/hip_runtime.h>
#include <hip/hip_bf16.h>

#define NUM_B 8
#define SEQ 1024
#define DIM 768
#define NH 12
#define DH 64

typedef __attribute__((ext_vector_type(8))) short bf16x8;
typedef __attribute__((ext_vector_type(4))) float floatx4;
typedef __attribute__((ext_vector_type(16))) float floatx16;
typedef __attribute__((ext_vector_type(4))) unsigned short ushortx4;
typedef __attribute__((ext_vector_type(8))) unsigned short ushortx8;

__device__ __forceinline__ unsigned short f2bf(float f) {
  unsigned u = __float_as_uint(f);
  u += 0x7FFFu + ((u >> 16) & 1u);   // round-to-nearest-even
  return (unsigned short)(u >> 16);
}

// async global->LDS, 16B per lane; LDS dest = wave-uniform base + lane*16
#define GLOAD16(g, l) __builtin_amdgcn_global_load_lds( \
    (const __attribute__((address_space(1))) unsigned int*)(g), \
    (__attribute__((address_space(3))) unsigned int*)(l), 16, 0, 0)

// ---------------- one-shot fp32 -> bf16 conversion (x, Wk, Wo) -------------
__global__ __launch_bounds__(256) void convert_kernel(
    const float* __restrict__ x, const float* __restrict__ Wk,
    const float* __restrict__ Wo, unsigned short* __restrict__ xb,
    unsigned short* __restrict__ Wkb, unsigned short* __restrict__ Wob)
{
  const int NX4 = (8192 * 768) / 4;
  const int NW4 = (768 * 768) / 4;
  int i = blockIdx.x * 256 + threadIdx.x;
  const float* s; unsigned short* d; int off;
  if (i < NX4)            { s = x;  d = xb;  off = i; }
  else if (i < NX4 + NW4) { s = Wk; d = Wkb; off = i - NX4; }
  else                    { s = Wo; d = Wob; off = i - NX4 - NW4; }
  float4 v = ((const float4*)s)[off];
  ushortx4 h;
  h.x = f2bf(v.x); h.y = f2bf(v.y); h.z = f2bf(v.z); h.w = f2bf(v.w);
  ((ushortx4*)d)[off] = h;
}

// ---------------- K projection + fused transpose ---------------------------
// RESTRUCTURED: tile 128(M) x 192(N), BK=64, 512 threads = 8 waves (2M x 4N),
// grid 256 = EXACTLY 1 block/CU (768/192=4 N-tiles x 64 M-tiles; zero
// imbalance). Per wave: 64x48 output (4x3 acc), 24 MFMA/iter; 3x per-block
// work amortizes the barrier convoy + staging issue. Same verified fragment
// algebra / XOR swizzle / gload_lds staging as the old 64x128 structure.
__global__ __launch_bounds__(512) void proj_k_kernel(
    const unsigned short* __restrict__ xb, const unsigned short* __restrict__ Wkb,
    const float* __restrict__ bk, unsigned short* __restrict__ Kbh,
    unsigned short* __restrict__ KbhT)
{
  __shared__ __align__(16) unsigned short smem[40960];   // 80 KB (2 x 40 KB)
  const int tid = threadIdx.x;
  const int lane = tid & 63;
  const int w = tid >> 6;                // 0..7
  const int wr = w >> 2, wc = w & 3;     // M-half / N-quarter
  const int quad = lane >> 4, r16 = lane & 15;
  const int rs = r16 & 7;
  const int m0 = (blockIdx.x & 63) * 128, n0 = (blockIdx.x >> 6) * 192;
  const int wbase = (tid & ~63);

  floatx4 acc[4][3] = {};

  auto stage = [&](int kt, int buf) {
    unsigned short* As = smem + buf * 20480;             // [128][64]
    unsigned short* Bs = As + 8192;                      // [192][64]
#pragma unroll
    for (int i = 0; i < 2; ++i) {
      int c = tid + i * 512;
      int row = c >> 3, g = (c & 7) ^ (row & 7);
      GLOAD16(xb + (size_t)(m0 + row) * DIM + kt + g * 8,
              As + (size_t)(wbase + i * 512) * 8);
    }
#pragma unroll
    for (int i = 0; i < 3; ++i) {
      int c = tid + i * 512;
      int row = c >> 3, g = (c & 7) ^ (row & 7);
      GLOAD16(Wkb + (size_t)(n0 + row) * DIM + kt + g * 8,
              Bs + (size_t)(wbase + i * 512) * 8);
    }
  };

  stage(0, 0);
  int buf = 0;
  for (int it = 0; it < 12; ++it) {
    __syncthreads();
    if (it + 1 < 12) stage((it + 1) * 64, buf ^ 1);
    const unsigned short* As = smem + buf * 20480;
    const unsigned short* Bs = As + 8192;
    bf16x8 af[4][2], bfm[3][2];
#pragma unroll
    for (int mi = 0; mi < 4; ++mi)
#pragma unroll
      for (int kc = 0; kc < 2; ++kc)
        af[mi][kc] = *(const bf16x8*)&As[(wr * 64 + mi * 16 + r16) * 64 + ((kc * 4 + quad) ^ rs) * 8];
#pragma unroll
    for (int ni = 0; ni < 3; ++ni)
#pragma unroll
      for (int kc = 0; kc < 2; ++kc)
        bfm[ni][kc] = *(const bf16x8*)&Bs[(wc * 48 + ni * 16 + r16) * 64 + ((kc * 4 + quad) ^ rs) * 8];
#pragma unroll
    for (int mi = 0; mi < 4; ++mi)
#pragma unroll
      for (int ni = 0; ni < 3; ++ni) {
        acc[mi][ni] = __builtin_amdgcn_mfma_f32_16x16x32_bf16(af[mi][0], bfm[ni][0], acc[mi][ni], 0, 0, 0);
        acc[mi][ni] = __builtin_amdgcn_mfma_f32_16x16x32_bf16(af[mi][1], bfm[ni][1], acc[mi][ni], 0, 0, 0);
      }
    buf ^= 1;
  }

  __syncthreads();                       // reuse smem as Ct [192 n][136]
  unsigned short* Ct = smem;             // 192*136 = 26112 shorts = 52 KB
  const int bb = m0 >> 10, l0 = m0 & 1023;   // 128-row tiles never straddle b
#pragma unroll
  for (int mi = 0; mi < 4; ++mi)
#pragma unroll
    for (int ni = 0; ni < 3; ++ni) {
      int col = n0 + wc * 48 + ni * 16 + r16;   // j = h*64+dh
      float bias = bk[col];
      int hh = col >> 6, dd = col & 63;
      ushortx4 pk;
#pragma unroll
      for (int r = 0; r < 4; ++r) {
        int mrow = wr * 64 + mi * 16 + quad * 4 + r;
        unsigned short us = f2bf(acc[mi][ni][r] + bias);
        Kbh[((size_t)(bb * NH + hh) * SEQ + l0 + mrow) * DH + dd] = us;
        pk[r] = us;
      }
      *(ushortx4*)&Ct[(wc * 48 + ni * 16 + r16) * 136 + wr * 64 + mi * 16 + quad * 4] = pk;
    }
  __syncthreads();
#pragma unroll
  for (int i = 0; i < 6; ++i) {          // 192 rows x 16 chunks of 8
    int c = tid + i * 512;
    int row = c >> 4, ch = c & 15;
    ushortx8 v = *(const ushortx8*)&Ct[row * 136 + ch * 8];
    int j = n0 + row;
    int hh = j >> 6, dd = j & 63;
    *(ushortx8*)&KbhT[((size_t)(bb * NH + hh) * DH + dd) * SEQ + l0 + ch * 8] = v;
  }
}

// ---------------- fused attention (FROZEN, R11-verified: 47.7 us) ----------
// 1-D grid 768, 256 threads = 4 waves x 32 q. 32x32x16 swapped QK^T,
// in-register softmax, permlane32_swap P exchange.
__global__ __launch_bounds__(256) void attn_kernel(
    const unsigned short* __restrict__ Kbh, const unsigned short* __restrict__ KbhT,
    const int* __restrict__ mask, unsigned short* __restrict__ wV)
{
  __shared__ __align__(16) unsigned short smem[16384];   // 32 KB: Ks/KTs dbuf

  const int tid = threadIdx.x;
  const int lane = tid & 63;
  const int w = tid >> 6;                // 0..3
  const int q = lane & 31;               // lane's q within the wave's 32-q tile
  const int hh = lane >> 5;              // half-wave (k-slot group)
  const int q7 = q & 7;                  // XOR swizzle key (row&7)
  // XCD-aware bijective decode (XCD = linear%8 round-robin assumption):
  const int Lb = blockIdx.x;
  const int qt = (Lb >> 3) & 7;
  const int bh = (Lb >> 6) * 8 + (Lb & 7);
  const int b = bh / NH, h = bh % NH;
  const unsigned short* Kb  = Kbh  + (size_t)bh * SEQ * DH;
  const unsigned short* KbT = KbhT + (size_t)bh * DH * SEQ;
  const int q0 = qt * 128;
  const int qw = w * 32;                 // wave's 32-q range within tile
  const int wbase = (tid & ~63);
  // 1/sqrt(768) * log2(e): exp(x*s) == exp2(x*s*log2e)
  const float SCALE2 = 0.036084391824351615f * 1.4426950408889634f;

  // mask folded into scale: masked row -> Q=0 -> St=0 -> p=1 (uniform softmax)
  const float scm = (mask[b * SEQ + q0 + qw + q] != 0) ? SCALE2 : 0.0f;

  // Q fragments, pre-scaled by scm (B-operand: col=q=lane&31, k=d=s*16+hh*8+j)
  bf16x8 aq[4];
#pragma unroll
  for (int s = 0; s < 4; ++s) {
    bf16x8 v = *(const bf16x8*)(Kb + (size_t)(q0 + qw + q) * DH + s * 16 + hh * 8);
    ushortx8 u; __builtin_memcpy(&u, &v, 16);
    ushortx8 o;
#pragma unroll
    for (int j = 0; j < 8; j += 2) {
      float f0 = __uint_as_float(((unsigned)u[j]) << 16) * scm;
      float f1 = __uint_as_float(((unsigned)u[j + 1]) << 16) * scm;
      __hip_bfloat162 hcv = __float22bfloat162_rn(make_float2(f0, f1));
      unsigned hu; __builtin_memcpy(&hu, &hcv, 4);
      o[j] = (unsigned short)(hu & 0xffffu);
      o[j + 1] = (unsigned short)(hu >> 16);
    }
    __builtin_memcpy(&aq[s], &o, 16);
  }

  floatx16 accO[2] = {};                 // O^T[d0*32+row][q], d0 = 0,1
  float psum = 0.0f;

  auto stage = [&](int kt, int buf) {
    unsigned short* Ks  = smem + buf * 4096;
    unsigned short* KTs = smem + 8192 + buf * 4096;
    // 256 threads x 16B x 2 passes per 64x64 bf16 tile
#pragma unroll
    for (int i = 0; i < 2; ++i) {
      int c = tid + i * 256;
      int row = c >> 3, g = (c & 7) ^ (row & 7);
      GLOAD16(Kb + (size_t)(kt + row) * DH + g * 8,
              Ks + (size_t)(wbase + i * 256) * 8);
    }
#pragma unroll
    for (int i = 0; i < 2; ++i) {
      int c = tid + i * 256;
      int row = c >> 3, g = (c & 7) ^ (row & 7);
      GLOAD16(KbT + (size_t)row * SEQ + kt + g * 8,
              KTs + (size_t)(wbase + i * 256) * 8);
    }
  };

  stage(0, 0);
  int buf = 0;
  for (int it = 0; it < SEQ / 64; ++it) {
    __syncthreads();
    if (it + 1 < SEQ / 64) stage((it + 1) * 64, buf ^ 1);
    const unsigned short* Ks  = smem + buf * 4096;
    const unsigned short* KTs = smem + 8192 + buf * 4096;

    bf16x8 pa[4];                        // PV B-frags: key steps s=0..3

#pragma unroll
    for (int kt = 0; kt < 2; ++kt) {
      // St[key][q] over 32 keys: A = K-frag (row=key=kt*32+q', k=d), B = aq
      floatx16 St = {};
      __builtin_amdgcn_s_setprio(1);
#pragma unroll
      for (int s = 0; s < 4; ++s) {
        bf16x8 kf = *(const bf16x8*)&Ks[(kt * 32 + q) * 64 + ((2 * s + hh) ^ q7) * 8];
        St = __builtin_amdgcn_mfma_f32_32x32x16_bf16(kf, aq[s], St, 0, 0, 0);
      }
      __builtin_amdgcn_s_setprio(0);

      // softmax partials in-register; pack pairs to bf16.
      // reg r -> key kt*32 + (r&3)+8*(r>>2)+4*hh
      unsigned pk[8];
#pragma unroll
      for (int j = 0; j < 8; ++j) {
        float pa_ = __builtin_amdgcn_exp2f(St[2 * j]);
        float pb_ = __builtin_amdgcn_exp2f(St[2 * j + 1]);
        psum += pa_ + pb_;
        __hip_bfloat162 hcv = __float22bfloat162_rn(make_float2(pa_, pb_));
        __builtin_memcpy(&pk[j], &hcv, 4);
      }
      // cross-half exchange via permlane32_swap: vdst.HI <-> vsrc.LO.
      unsigned w0 = pk[0], w1 = pk[1], w2 = pk[2], w3 = pk[3];
      unsigned w4 = pk[4], w5 = pk[5], w6 = pk[6], w7 = pk[7];
      asm("v_permlane32_swap_b32 %0, %1" : "+v"(w0), "+v"(w2));
      asm("v_permlane32_swap_b32 %0, %1" : "+v"(w1), "+v"(w3));
      asm("v_permlane32_swap_b32 %0, %1" : "+v"(w4), "+v"(w6));
      asm("v_permlane32_swap_b32 %0, %1" : "+v"(w5), "+v"(w7));
      uint4 B0 = make_uint4(w0, w1, w2, w3);
      uint4 B1 = make_uint4(w4, w5, w6, w7);
      __builtin_memcpy(&pa[kt * 2 + 0], &B0, 16);
      __builtin_memcpy(&pa[kt * 2 + 1], &B1, 16);
    }

    // O^T[d][q] += V^T[d][key] P^T[key][q]; A = V^T-frag from KTs
    __builtin_amdgcn_s_setprio(1);
#pragma unroll
    for (int d0 = 0; d0 < 2; ++d0)
#pragma unroll
      for (int s = 0; s < 4; ++s) {
        bf16x8 vf = *(const bf16x8*)&KTs[(d0 * 32 + q) * 64 + ((2 * s + hh) ^ q7) * 8];
        accO[d0] = __builtin_amdgcn_mfma_f32_32x32x16_bf16(vf, pa[s], accO[d0], 0, 0, 0);
      }
    __builtin_amdgcn_s_setprio(0);
    buf ^= 1;
  }

  // lane holds sums over its 16-key half (all tiles); partner has the rest.
  psum += __shfl_xor(psum, 32);
  float rinv = 1.0f / psum;

  // accO C-layout: col=q (this lane's q), row d = (r&3)+8*(r>>2)+4*hh
  const size_t orow = (size_t)(b * SEQ + q0 + qw + q) * DIM + h * DH;
#pragma unroll
  for (int d0 = 0; d0 < 2; ++d0)
#pragma unroll
    for (int rg = 0; rg < 4; ++rg) {
      ushortx4 st;
#pragma unroll
      for (int i = 0; i < 4; ++i)
        st[i] = f2bf(accO[d0][rg * 4 + i] * rinv);
      *(ushortx4*)&wV[orow + d0 * 32 + rg * 8 + hh * 4] = st;
    }
}

// ---------------- output projection (FROZEN control): out = wV @ Wo^T + bo -
__global__ __launch_bounds__(256) void proj_o_kernel(
    const unsigned short* __restrict__ wVb, const unsigned short* __restrict__ Wob,
    const float* __restrict__ bo, float* __restrict__ out)
{
  __shared__ __align__(16) unsigned short smem[24576];   // 48 KB
  const int tid = threadIdx.x;
  const int lane = tid & 63;
  const int w = tid >> 6;
  const int wr = w >> 1, wc = w & 1;
  const int quad = lane >> 4, r16 = lane & 15;
  const int rs = r16 & 7;
  const int m0 = blockIdx.x * 64, n0 = blockIdx.y * 128;
  const int wbase = (tid & ~63);

  floatx4 acc[2][4] = {};

  auto stage = [&](int kt, int buf) {
    unsigned short* As = smem + buf * 12288;
    unsigned short* Bs = As + 4096;
#pragma unroll
    for (int i = 0; i < 2; ++i) {
      int c = tid + i * 256;
      int row = c >> 3, g = (c & 7) ^ (row & 7);
      GLOAD16(wVb + (size_t)(m0 + row) * DIM + kt + g * 8,
              As + (size_t)(wbase + i * 256) * 8);
    }
#pragma unroll
    for (int i = 0; i < 4; ++i) {
      int c = tid + i * 256;
      int row = c >> 3, g = (c & 7) ^ (row & 7);
      GLOAD16(Wob + (size_t)(n0 + row) * DIM + kt + g * 8,
              Bs + (size_t)(wbase + i * 256) * 8);
    }
  };

  stage(0, 0);
  int buf = 0;
  for (int it = 0; it < 12; ++it) {
    __syncthreads();
    if (it + 1 < 12) stage((it + 1) * 64, buf ^ 1);
    const unsigned short* As = smem + buf * 12288;
    const unsigned short* Bs = As + 4096;
    bf16x8 af[2][2], bfm[4][2];
#pragma unroll
    for (int mi = 0; mi < 2; ++mi)
#pragma unroll
      for (int kc = 0; kc < 2; ++kc)
        af[mi][kc] = *(const bf16x8*)&As[(wr * 32 + mi * 16 + r16) * 64 + ((kc * 4 + quad) ^ rs) * 8];
#pragma unroll
    for (int ni = 0; ni < 4; ++ni)
#pragma unroll
      for (int kc = 0; kc < 2; ++kc)
        bfm[ni][kc] = *(const bf16x8*)&Bs[(wc * 64 + ni * 16 + r16) * 64 + ((kc * 4 + quad) ^ rs) * 8];
#pragma unroll
    for (int mi = 0; mi < 2; ++mi)
#pragma unroll
      for (int ni = 0; ni < 4; ++ni) {
        acc[mi][ni] = __builtin_amdgcn_mfma_f32_16x16x32_bf16(af[mi][0], bfm[ni][0], acc[mi][ni], 0, 0, 0);
        acc[mi][ni] = __builtin_amdgcn_mfma_f32_16x16x32_bf16(af[mi][1], bfm[ni][1], acc[mi][ni], 0, 0, 0);
      }
    buf ^= 1;
  }

#pragma unroll
  for (int mi = 0; mi < 2; ++mi)
#pragma unroll
    for (int ni = 0; ni < 4; ++ni) {
      int col = n0 + wc * 64 + ni * 16 + r16;
      float bias = bo[col];
#pragma unroll
      for (int r = 0; r < 4; ++r) {
        int row = m0 + wr * 32 + mi * 16 + quad * 4 + r;
        out[(size_t)row * DIM + col] = acc[mi][ni][r] + bias;
      }
    }
}

extern "C" void kernel_launch(void* const* d_in, const int* in_sizes, int n_in,
                              void* d_out, int out_size, void* d_ws, size_t ws_size,
                              hipStream_t stream) {
  // inputs: x, attention_mask, Wq, bq, Wk, bk, Wv, bv, Wo, bo  (Q dead; V==K)
  const float* x  = (const float*)d_in[0];
  const int* mask = (const int*)d_in[1];
  const float* Wk = (const float*)d_in[4];
  const float* bk = (const float*)d_in[5];
  const float* Wo = (const float*)d_in[8];
  const float* bo = (const float*)d_in[9];
  float* out = (float*)d_out;

  unsigned short* p = (unsigned short*)d_ws;
  unsigned short* xb   = p;  p += (size_t)8192 * 768;
  unsigned short* Wkb  = p;  p += (size_t)768 * 768;
  unsigned short* Wob  = p;  p += (size_t)768 * 768;
  unsigned short* Kbh  = p;  p += (size_t)NUM_B * NH * SEQ * DH;
  unsigned short* KbhT = p;  p += (size_t)NUM_B * NH * SEQ * DH;
  unsigned short* wVb  = p;  // [8192][768]

  convert_kernel<<<7296, 256, 0, stream>>>(x, Wk, Wo, xb, Wkb, Wob);
  proj_k_kernel<<<256, 512, 0, stream>>>(xb, Wkb, bk, Kbh, KbhT);
  attn_kernel<<<768, 256, 0, stream>>>(Kbh, KbhT, mask, wVb);
  proj_o_kernel<<<dim3(128, 6), 256, 0, stream>>>(wVb, Wob, bo, out);
}